// Round 7
// baseline (541.532 us; speedup 1.0000x reference)
//
#include <hip/hip_runtime.h>

#define B_  32
#define T_  256
#define F_  64
#define C_  16
#define CO_ 16
#define P_  64
#define S_  32
#define K_  4
#define FC_ 1024   // F*C
#define OUTC 96
#define TT  8      // t-tile per block
#define NS  14     // TT + 6 halo slices (dilation*(K-1) = 6)

typedef float floatx4 __attribute__((ext_vector_type(4)));

// LDS-only barrier: drains lgkmcnt but leaves global stores in flight
// (output is never re-read; staging reuse only needs LDS visibility).
#define BARRIER_LGKM() asm volatile("s_waitcnt lgkmcnt(0)\n\ts_barrier" ::: "memory")

__global__ __launch_bounds__(512, 4) void tpc_fused(
    const float* __restrict__ x, const float* __restrict__ stat,
    const float* __restrict__ cw, const float* __restrict__ cb,
    const float* __restrict__ Wp, const float* __restrict__ bp,
    float* __restrict__ out)
{
    __shared__ __align__(16) float xs[NS * FC_];   // 57.3 KB
    // u: phase 1 = partials [0,4096); phase 1b result (relu point) [3072,3584)
    //    phase 2 = double-buffered output staging: bufA [0,1024), bufB [1024,2048)
    __shared__ __align__(16) float u[4096];        // 16 KB -> 73.7 KB total, 2 blk/CU

    int tid = threadIdx.x;
    int blk = blockIdx.x;      // 0..1023
    int b  = blk >> 5;
    int t0 = (blk & 31) * TT;

    // ---- stage x[t0-6 .. t0+TT-1, :, :] into LDS (zero left pad) ----
    #pragma unroll
    for (int it = 0; it < 7; ++it) {
        int v = it * 512 + tid;            // float4 id, NS*256 = 3584 total
        int slice = v >> 8;
        int pos   = v & 255;
        int tg = t0 - 6 + slice;
        float4 val = make_float4(0.f, 0.f, 0.f, 0.f);
        if (tg >= 0)
            val = *(const float4*)(x + ((size_t)(b * T_ + tg)) * FC_ + pos * 4);
        *(float4*)(xs + slice * FC_ + pos * 4) = val;
    }
    __syncthreads();

    // ---- phase 1: point GEMM partials; wave = one 128-wide k slice ----
    {
        int p  = tid & 63;
        int ks = tid >> 6;                 // 0..7
        float acc[TT];
        #pragma unroll
        for (int r = 0; r < TT; ++r) acc[r] = 0.f;
        int k0base = ks * 128;
        for (int kk = 0; kk < 128; kk += 4) {
            int k0 = k0base + kk;
            float w0 = Wp[(size_t)(k0 + 0) * P_ + p];
            float w1 = Wp[(size_t)(k0 + 1) * P_ + p];
            float w2 = Wp[(size_t)(k0 + 2) * P_ + p];
            float w3 = Wp[(size_t)(k0 + 3) * P_ + p];
            #pragma unroll
            for (int r = 0; r < TT; ++r) {
                float4 xv = *(const float4*)(xs + (6 + r) * FC_ + k0);
                acc[r] += xv.x * w0 + xv.y * w1 + xv.z * w2 + xv.w * w3;
            }
        }
        #pragma unroll
        for (int r = 0; r < TT; ++r)
            u[(ks * TT + r) * P_ + p] = acc[r];
    }
    __syncthreads();

    // ---- phase 1b: reduce + bias + static; relu into u[3072..3584) ----
    {
        int p = tid & 63;
        int r = tid >> 6;                  // row 0..7
        float s = bp[p];
        const float* wst = Wp + (size_t)FC_ * P_;
        #pragma unroll 8
        for (int si = 0; si < S_; ++si)
            s += stat[b * S_ + si] * wst[si * P_ + p];
        #pragma unroll
        for (int ks = 0; ks < 8; ++ks)
            s += u[(ks * TT + r) * P_ + p];
        __syncthreads();                   // all partial reads done before overwrite
        u[3072 + r * P_ + p] = fmaxf(s, 0.f);
    }
    __syncthreads();

    // ---- point broadcast: direct register->global stores ----
    // Channels [32,96) of each f-record: 256B line-aligned segments, no RFO.
    // Fire-and-forget; overlaps the conv compute below. No barrier ever needed.
    {
        int pp = tid & 15;                 // float4 index within p
        int fq = tid >> 4;                 // 0..31
        for (int tl = 0; tl < TT; ++tl) {
            floatx4 v4 = *(const floatx4*)(u + 3072 + tl * P_ + pp * 4);
            float* ob = out + ((size_t)(b * T_ + t0 + tl)) * F_ * OUTC + 32 + pp * 4;
            __builtin_nontemporal_store(v4, (floatx4*)(ob + (size_t)fq * OUTC));
            __builtin_nontemporal_store(v4, (floatx4*)(ob + (size_t)(32 + fq) * OUTC));
        }
    }

    // ---- phase 2: conv via slice loop (x read once per slice, 4 taps applied),
    //      staged dump of channels [0,32) with double-buffered LDS ----
    int co = tid & 15;
    int fh = tid >> 4;                     // 0..31 (local f within half)

    #pragma unroll
    for (int half = 0; half < 2; ++half) {
        int f = half * 32 + fh;
        // conv weights for (f, co): 64 floats (cw read once per block total)
        float w[64];
        const float4* wg = (const float4*)(cw + ((size_t)(f * CO_ + co)) * (C_ * K_));
        #pragma unroll
        for (int j = 0; j < 16; ++j) {
            float4 t4 = wg[j];
            w[4 * j + 0] = t4.x; w[4 * j + 1] = t4.y;
            w[4 * j + 2] = t4.z; w[4 * j + 3] = t4.w;
        }
        float bias = cb[f * CO_ + co];

        float acc[TT];
        #pragma unroll
        for (int r = 0; r < TT; ++r) acc[r] = bias;

        // slice loop: 14 slices x 4 b128 reads, each applied to up to 4 tl accs.
        // Per-acc accumulation order (s ascending = k ascending, c inner) is
        // bit-identical to the per-tl k-loop formulation.
        #pragma unroll
        for (int s = 0; s < NS; ++s) {
            const float* sp = xs + s * FC_ + f * C_;
            float4 xv0 = *(const float4*)(sp + 0);
            float4 xv1 = *(const float4*)(sp + 4);
            float4 xv2 = *(const float4*)(sp + 8);
            float4 xv3 = *(const float4*)(sp + 12);
            #pragma unroll
            for (int k = 0; k < K_; ++k) {
                int tl = s - 2 * k;
                if (tl < 0 || tl >= TT) continue;   // folds at compile time
                acc[tl] += xv0.x * w[0 * 4 + k];  acc[tl] += xv0.y * w[1 * 4 + k];
                acc[tl] += xv0.z * w[2 * 4 + k];  acc[tl] += xv0.w * w[3 * 4 + k];
                acc[tl] += xv1.x * w[4 * 4 + k];  acc[tl] += xv1.y * w[5 * 4 + k];
                acc[tl] += xv1.z * w[6 * 4 + k];  acc[tl] += xv1.w * w[7 * 4 + k];
                acc[tl] += xv2.x * w[8 * 4 + k];  acc[tl] += xv2.y * w[9 * 4 + k];
                acc[tl] += xv2.z * w[10 * 4 + k]; acc[tl] += xv2.w * w[11 * 4 + k];
                acc[tl] += xv3.x * w[12 * 4 + k]; acc[tl] += xv3.y * w[13 * 4 + k];
                acc[tl] += xv3.z * w[14 * 4 + k]; acc[tl] += xv3.w * w[15 * 4 + k];
            }
        }

        // output: stage conv + xpass (channels [0,32)) and dump, double-buffered
        for (int tl = 0; tl < TT; ++tl) {
            float* buf = u + (tl & 1) * 1024;
            buf[fh * 32 + 16 + co] = fmaxf(acc[tl], 0.f);
            buf[fh * 32 + co] = fmaxf(xs[(tl + 6) * FC_ + f * C_ + co], 0.f);
            BARRIER_LGKM();                // stage visible; prev dump (other buf) done
            if (tid < 256) {
                int fl = tid >> 3;         // 0..31
                int q  = tid & 7;          // 0..7 -> channels [0,32)
                floatx4 v = *(const floatx4*)(buf + fl * 32 + q * 4);
                float* dst = out + ((size_t)(b * T_ + t0 + tl)) * F_ * OUTC
                             + (size_t)(half * 32 + fl) * OUTC + q * 4;
                __builtin_nontemporal_store(v, (floatx4*)dst);
            }
        }
    }
}

extern "C" void kernel_launch(void* const* d_in, const int* in_sizes, int n_in,
                              void* d_out, int out_size, void* d_ws, size_t ws_size,
                              hipStream_t stream) {
    const float* x    = (const float*)d_in[0];
    const float* stat = (const float*)d_in[1];
    const float* cw   = (const float*)d_in[2];
    const float* cb   = (const float*)d_in[3];
    const float* Wp   = (const float*)d_in[4];
    const float* bp   = (const float*)d_in[5];
    float* out = (float*)d_out;

    tpc_fused<<<1024, 512, 0, stream>>>(x, stat, cw, cb, Wp, bp, out);
}

// Round 8
// 288.703 us; speedup vs baseline: 1.8757x; 1.8757x over previous
//
#include <hip/hip_runtime.h>

#define B_  32
#define T_  256
#define F_  64
#define C_  16
#define CO_ 16
#define P_  64
#define S_  32
#define K_  4
#define FC_ 1024   // F*C
#define OUTC 96
#define TT  8      // t-tile per block
#define NS  14     // TT + 6 halo slices (dilation*(K-1) = 6)

typedef float floatx4 __attribute__((ext_vector_type(4)));

// LDS-only barrier: drains lgkmcnt but leaves global stores in flight.
#define BARRIER_LGKM() asm volatile("s_waitcnt lgkmcnt(0)\n\ts_barrier" ::: "memory")

// bf16 pack (round-to-nearest, ties-away) / exact unpack via shift.
__device__ __forceinline__ unsigned pk2(float a, float b) {
    unsigned ua = (__float_as_uint(a) + 0x8000u) >> 16;
    unsigned ub = (__float_as_uint(b) + 0x8000u) >> 16;
    return ua | (ub << 16);
}
__device__ __forceinline__ float lo16(unsigned w) { return __uint_as_float(w << 16); }
__device__ __forceinline__ float hi16(unsigned w) { return __uint_as_float(w & 0xFFFF0000u); }

__global__ __launch_bounds__(512, 4) void tpc_fused(
    const float* __restrict__ x, const float* __restrict__ stat,
    const float* __restrict__ cw, const float* __restrict__ cb,
    const float* __restrict__ Wp, const float* __restrict__ bp,
    float* __restrict__ out)
{
    // x staged as packed bf16 pairs: xh[slice][512 words] (word = 2 elems)
    __shared__ __align__(16) unsigned xh[NS * 512];   // 28 KB
    __shared__ __align__(16) float u[4096];           // 16 KB -> 44.7 KB total

    int tid = threadIdx.x;
    int blk = blockIdx.x;      // 0..1023
    int b  = blk >> 5;
    int t0 = (blk & 31) * TT;

    // ---- stage x[t0-6 .. t0+TT-1, :, :] -> bf16 LDS (zero left pad) ----
    #pragma unroll
    for (int it = 0; it < 7; ++it) {
        int v = it * 512 + tid;            // float4 id, NS*256 = 3584 total
        int slice = v >> 8;
        int pos   = v & 255;
        int tg = t0 - 6 + slice;
        float4 val = make_float4(0.f, 0.f, 0.f, 0.f);
        if (tg >= 0)
            val = *(const float4*)(x + ((size_t)(b * T_ + tg)) * FC_ + pos * 4);
        uint2 pw;
        pw.x = pk2(val.x, val.y);
        pw.y = pk2(val.z, val.w);
        *(uint2*)(xh + slice * 512 + pos * 2) = pw;
    }
    __syncthreads();

    // ---- phase 1: point GEMM partials; wave = one 128-wide k slice ----
    {
        int p  = tid & 63;
        int ks = tid >> 6;                 // 0..7
        float acc[TT];
        #pragma unroll
        for (int r = 0; r < TT; ++r) acc[r] = 0.f;
        int kw0 = ks * 64;                 // word index of this wave's k-slice
        for (int oct = 0; oct < 16; ++oct) {
            int wi = kw0 + oct * 4;        // uint4 word offset
            int ke = ks * 128 + oct * 8;   // element index
            float wv0 = Wp[(size_t)(ke + 0) * P_ + p];
            float wv1 = Wp[(size_t)(ke + 1) * P_ + p];
            float wv2 = Wp[(size_t)(ke + 2) * P_ + p];
            float wv3 = Wp[(size_t)(ke + 3) * P_ + p];
            float wv4 = Wp[(size_t)(ke + 4) * P_ + p];
            float wv5 = Wp[(size_t)(ke + 5) * P_ + p];
            float wv6 = Wp[(size_t)(ke + 6) * P_ + p];
            float wv7 = Wp[(size_t)(ke + 7) * P_ + p];
            #pragma unroll
            for (int r = 0; r < TT; ++r) {
                uint4 q = *(const uint4*)(xh + (6 + r) * 512 + wi);
                acc[r] += lo16(q.x) * wv0 + hi16(q.x) * wv1
                        + lo16(q.y) * wv2 + hi16(q.y) * wv3
                        + lo16(q.z) * wv4 + hi16(q.z) * wv5
                        + lo16(q.w) * wv6 + hi16(q.w) * wv7;
            }
        }
        #pragma unroll
        for (int r = 0; r < TT; ++r)
            u[(ks * TT + r) * P_ + p] = acc[r];
    }
    __syncthreads();

    // ---- phase 1b: reduce + bias + static (fp32 exact); relu -> u[3072..) ----
    {
        int p = tid & 63;
        int r = tid >> 6;                  // row 0..7
        float s = bp[p];
        const float* wst = Wp + (size_t)FC_ * P_;
        #pragma unroll 8
        for (int si = 0; si < S_; ++si)
            s += stat[b * S_ + si] * wst[si * P_ + p];
        #pragma unroll
        for (int ks = 0; ks < 8; ++ks)
            s += u[(ks * TT + r) * P_ + p];
        __syncthreads();                   // all partial reads done before overwrite
        u[3072 + r * P_ + p] = fmaxf(s, 0.f);
    }
    __syncthreads();

    // ---- phase 2: conv (bf16 x, bf16-packed weights) + staged dumps ----
    int co = tid & 15;
    int fh = tid >> 4;                     // 0..31 (local f within half)
    int p  = tid & 63;
    int fg = tid >> 6;                     // 0..7

    #pragma unroll
    for (int half = 0; half < 2; ++half) {
        int f = half * 32 + fh;
        // conv weights packed bf16: wp2[c*2+(k>>1)] holds (k even, k odd)
        unsigned wp2[32];
        const float4* wg = (const float4*)(cw + ((size_t)(f * CO_ + co)) * (C_ * K_));
        #pragma unroll
        for (int j = 0; j < 16; ++j) {
            float4 t4 = wg[j];             // one c's 4 k-taps
            wp2[j * 2 + 0] = pk2(t4.x, t4.y);
            wp2[j * 2 + 1] = pk2(t4.z, t4.w);
        }
        float bias = cb[f * CO_ + co];

        for (int tl = 0; tl < TT; ++tl) {
            float a = bias;
            #pragma unroll
            for (int k = 0; k < K_; ++k) {
                const unsigned* sp = xh + (tl + 2 * k) * 512 + f * 8;
                uint4 qa = *(const uint4*)sp;        // c 0..7
                uint4 qb = *(const uint4*)(sp + 4);  // c 8..15
                int h = k >> 1;
                #define WK(c) ((k & 1) ? hi16(wp2[(c)*2 + h]) : lo16(wp2[(c)*2 + h]))
                a += lo16(qa.x) * WK(0)  + hi16(qa.x) * WK(1);
                a += lo16(qa.y) * WK(2)  + hi16(qa.y) * WK(3);
                a += lo16(qa.z) * WK(4)  + hi16(qa.z) * WK(5);
                a += lo16(qa.w) * WK(6)  + hi16(qa.w) * WK(7);
                a += lo16(qb.x) * WK(8)  + hi16(qb.x) * WK(9);
                a += lo16(qb.y) * WK(10) + hi16(qb.y) * WK(11);
                a += lo16(qb.z) * WK(12) + hi16(qb.z) * WK(13);
                a += lo16(qb.w) * WK(14) + hi16(qb.w) * WK(15);
                #undef WK
            }
            // stage: conv result + exact-fp32 x passthrough (global, L2-hot)
            float xg = x[((size_t)(b * T_ + t0 + tl) * F_ + f) * C_ + co];
            u[fh * OUTC + 16 + co] = fmaxf(a, 0.f);
            u[fh * OUTC + co] = fmaxf(xg, 0.f);
            float pvv = u[3072 + tl * P_ + p];
            #pragma unroll
            for (int fo = 0; fo < 4; ++fo)
                u[(fo * 8 + fg) * OUTC + 32 + p] = pvv;
            BARRIER_LGKM();                // LDS-only drain
            {
                const floatx4* src = (const floatx4*)u;
                floatx4* dst = (floatx4*)(out + ((size_t)(b * T_ + t0 + tl)) * F_ * OUTC
                                          + half * 3072);
                __builtin_nontemporal_store(src[tid], &dst[tid]);
                if (tid < 256)
                    __builtin_nontemporal_store(src[512 + tid], &dst[512 + tid]);
            }
            BARRIER_LGKM();                // staging reuse; stores stay in flight
        }
    }
}

extern "C" void kernel_launch(void* const* d_in, const int* in_sizes, int n_in,
                              void* d_out, int out_size, void* d_ws, size_t ws_size,
                              hipStream_t stream) {
    const float* x    = (const float*)d_in[0];
    const float* stat = (const float*)d_in[1];
    const float* cw   = (const float*)d_in[2];
    const float* cb   = (const float*)d_in[3];
    const float* Wp   = (const float*)d_in[4];
    const float* bp   = (const float*)d_in[5];
    float* out = (float*)d_out;

    tpc_fused<<<1024, 512, 0, stream>>>(x, stat, cw, cb, Wp, bp, out);
}